// Round 11
// baseline (63.827 us; speedup 1.0000x reference)
//
#include <hip/hip_runtime.h>
#include <math.h>

#define NPOS 1024   // H*W
#define DH   32     // dim head
#define NBH  8      // B * HEADS
#define CH   256
#define INNER 128   // HEADS*DIM_HEAD

typedef __attribute__((ext_vector_type(4))) _Float16 half4;
typedef __attribute__((ext_vector_type(4))) float f32x4;

// Canonical CDNA 16x16x16 f16 MFMA.  A: row=l&15, k=4*(l>>4)+j.  B: col=l&15,
// same k ordering.  C/D: col=l&15, row=(l>>4)*4+reg.
#define MFMA16(a, b, c) __builtin_amdgcn_mfma_f32_16x16x16f16((a), (b), (c), 0, 0, 0)

union h2u { _Float16 h; unsigned short u; };

__device__ __forceinline__ unsigned short f2h(float f) {
  h2u c; c.h = (_Float16)f; return c.u;
}
__device__ __forceinline__ float h2f(unsigned short u) {
  h2u c; c.u = u; return (float)c.h;
}
__device__ __forceinline__ half4 ldh4(const unsigned short* __restrict__ p) {
  union { half4 v; uint2 u; } r;
  r.u = *(const uint2*)p;
  return r.v;
}

// ---------------------------------------------------------------------------
// Kernel A: fused QKV projection + split-f16 encode, x tile staged in LDS.
// Qhi/Qlo/Khi/Klo: [bh][n][d] (d-contiguous).  Vthi/Vtlo: [bh][d][n].
// Q pre-scaled by 1/sqrt(dh).  Weights via wave-uniform s_loads
// (readfirstlane); x loaded ONCE per WG per tile (was 4x per wave).
// ---------------------------------------------------------------------------
__global__ __launch_bounds__(256) void proj_kernel(
    const float* __restrict__ x, const float* __restrict__ Wq,
    const float* __restrict__ Wk, const float* __restrict__ Wv,
    unsigned short* __restrict__ Qhi, unsigned short* __restrict__ Qlo,
    unsigned short* __restrict__ Khi, unsigned short* __restrict__ Klo,
    unsigned short* __restrict__ Vthi, unsigned short* __restrict__ Vtlo)
{
  __shared__ float xs[64][64];   // [c][n] tile, 16 KB

  const int tid  = threadIdx.x;
  const int lane = tid & 63;
  const int it   = __builtin_amdgcn_readfirstlane(tid >> 6); // 0..3, SGPR
  const int n    = blockIdx.x * 64 + lane;  // 0..1023
  const int i0   = blockIdx.y * 8 + it * 2; // even, 0..126 (wave-uniform)
  const int b    = blockIdx.z;

  const float* xb = x  + (size_t)b * CH * NPOS + (size_t)blockIdx.x * 64;
  const float* wq = Wq + (size_t)i0 * CH;
  const float* wk = Wk + (size_t)i0 * CH;
  const float* wv = Wv + (size_t)i0 * CH;

  float aq0 = 0.f, aq1 = 0.f, ak0 = 0.f, ak1 = 0.f, av0 = 0.f, av1 = 0.f;

  const int srow = tid >> 4;          // 0..15 (row base for staging)
  const int scol = (tid & 15) * 4;    // float4 col

  for (int c0 = 0; c0 < CH; c0 += 64) {
    if (c0) __syncthreads();
    // stage 64c x 64n: 4 float4 per thread, coalesced
    #pragma unroll
    for (int j = 0; j < 4; ++j) {
      const int r = srow + 16 * j;
      *(float4*)&xs[r][scol] =
          *(const float4*)&xb[(size_t)(c0 + r) * NPOS + scol];
    }
    __syncthreads();

    #pragma unroll 16
    for (int cc = 0; cc < 64; ++cc) {
      const float xv = xs[cc][lane];
      const int c = c0 + cc;
      aq0 += wq[c]      * xv;
      aq1 += wq[CH + c] * xv;
      ak0 += wk[c]      * xv;
      ak1 += wk[CH + c] * xv;
      av0 += wv[c]      * xv;
      av1 += wv[CH + c] * xv;
    }
  }

  const float qs = 0.17677669529663687f;  // 1/sqrt(32)
  aq0 *= qs;  aq1 *= qs;

  const int h = i0 >> 5, d = i0 & 31, bh = b * 4 + h;

  unsigned short qh0 = f2h(aq0), qh1 = f2h(aq1);
  unsigned short ql0 = f2h(aq0 - h2f(qh0)), ql1 = f2h(aq1 - h2f(qh1));
  unsigned short kh0 = f2h(ak0), kh1 = f2h(ak1);
  unsigned short kl0 = f2h(ak0 - h2f(kh0)), kl1 = f2h(ak1 - h2f(kh1));
  unsigned short vh0 = f2h(av0), vh1 = f2h(av1);
  unsigned short vl0 = f2h(av0 - h2f(vh0)), vl1 = f2h(av1 - h2f(vh1));

  const size_t qk = ((size_t)bh * NPOS + n) * DH + d;   // d even -> 4B aligned
  *(unsigned int*)(Qhi + qk) = (unsigned int)qh0 | ((unsigned int)qh1 << 16);
  *(unsigned int*)(Qlo + qk) = (unsigned int)ql0 | ((unsigned int)ql1 << 16);
  *(unsigned int*)(Khi + qk) = (unsigned int)kh0 | ((unsigned int)kh1 << 16);
  *(unsigned int*)(Klo + qk) = (unsigned int)kl0 | ((unsigned int)kl1 << 16);

  const size_t vt = ((size_t)bh * DH + d) * NPOS + n;
  Vthi[vt]        = vh0;
  Vthi[vt + NPOS] = vh1;
  Vtlo[vt]        = vl0;
  Vtlo[vt + NPOS] = vl1;
}

// ---------------------------------------------------------------------------
// Kernel B: fully fused attention (UNCHANGED from passing R9/R10 version).
// S^T = K·Q^T; KAN + exp(kan-Bnd) in-register; f16 P = B-operand fragment
// for O^T = V^T·P^T; denominator sums same f16-rounded p; 8-way LDS combine.
// ---------------------------------------------------------------------------
__global__ __launch_bounds__(512) void attn_fused(
    const unsigned short* __restrict__ Qhi, const unsigned short* __restrict__ Qlo,
    const unsigned short* __restrict__ Khi, const unsigned short* __restrict__ Klo,
    const unsigned short* __restrict__ Vthi, const unsigned short* __restrict__ Vtlo,
    const float* __restrict__ bwp, const float* __restrict__ swp,
    const float* __restrict__ ssp, float* __restrict__ Onorm)
{
  __shared__ float DlO[8][32][17];
  __shared__ float DlS[8][4][17];

  const int tid = threadIdx.x;
  const int l   = tid & 63;
  const int w   = tid >> 6;        // 0..7
  const int lr  = l & 15;
  const int lg  = l >> 4;          // 0..3
  const int ko  = lg * 4;
  const int bh  = blockIdx.x;      // 0..7 (== XCD)
  const int q0  = blockIdx.y * 16;

  // ---- uniform KAN constants ----
  const float sc = ssp[0];
  const float bw = bwp[0];
  float C[8];
  #pragma unroll
  for (int j = 0; j < 8; ++j) C[j] = swp[j] * sc;
  float maxc = 0.f;
  #pragma unroll
  for (int j = 0; j < 8; ++j) maxc = fmaxf(maxc, fabsf(C[j]));
  const float Bnd = fabsf(bw) * 6.0f + maxc;    // >= max_x kan(x)

  float A0[5], A1[5], A2[5], A3[5];             // per-cell cubic; -Bnd in A0
  #pragma unroll
  for (int c = 0; c < 5; ++c) {
    A0[c] = (C[c] + 4.f * C[c+1] + C[c+2]) * (1.f / 6.f) - Bnd;
    A1[c] = (-3.f * C[c] + 3.f * C[c+2]) * (1.f / 6.f);
    A2[c] = (3.f * C[c] - 6.f * C[c+1] + 3.f * C[c+2]) * (1.f / 6.f);
    A3[c] = (-C[c] + 3.f * C[c+1] - 3.f * C[c+2] + C[c+3]) * (1.f / 6.f);
  }

  // ---- Q fragments (B-operand, persistent): col q = q0+lr, k-dim d ----
  const size_t qb = ((size_t)bh * NPOS + q0 + lr) * DH;
  const half4 Bq_h0 = ldh4(Qhi + qb + ko);
  const half4 Bq_h1 = ldh4(Qhi + qb + 16 + ko);
  const half4 Bq_l0 = ldh4(Qlo + qb + ko);
  const half4 Bq_l1 = ldh4(Qlo + qb + 16 + ko);

  // ---- V^T bases (A-operand): row d = lr (+16), k = key ----
  const unsigned short* vh0 = Vthi + ((size_t)bh * DH + lr) * NPOS;
  const unsigned short* vh1 = vh0 + (size_t)16 * NPOS;
  const unsigned short* vl0 = Vtlo + ((size_t)bh * DH + lr) * NPOS;
  const unsigned short* vl1 = vl0 + (size_t)16 * NPOS;

  f32x4 accO0 = {0.f, 0.f, 0.f, 0.f};   // d 0..15
  f32x4 accO1 = {0.f, 0.f, 0.f, 0.f};   // d 16..31
  float ssum = 0.f;

  #pragma unroll 2
  for (int t = 0; t < 8; ++t) {
    const int k0 = w * 128 + t * 16;

    // ---- QK: A = K rows k0+lr ----
    const size_t kb2 = ((size_t)bh * NPOS + k0 + lr) * DH;
    const half4 Ak_h0 = ldh4(Khi + kb2 + ko);
    const half4 Ak_h1 = ldh4(Khi + kb2 + 16 + ko);
    const half4 Ak_l0 = ldh4(Klo + kb2 + ko);
    const half4 Ak_l1 = ldh4(Klo + kb2 + 16 + ko);

    f32x4 acc = {0.f, 0.f, 0.f, 0.f};
    acc = MFMA16(Ak_h0, Bq_h0, acc);
    acc = MFMA16(Ak_h1, Bq_h1, acc);
    acc = MFMA16(Ak_h0, Bq_l0, acc);
    acc = MFMA16(Ak_h1, Bq_l1, acc);
    acc = MFMA16(Ak_l0, Bq_h0, acc);
    acc = MFMA16(Ak_l1, Bq_h1, acc);
    // acc[r] = S[q=q0+lr][k = k0+4*lg+r]

    // ---- KAN + exp(kan - Bnd) on 4 values; keep f16-consistent p ----
    unsigned short ph[4];
    #pragma unroll
    for (int r = 0; r < 4; ++r) {
      float s = acc[r];
      s = fminf(fmaxf(s, -6.0f), 6.0f);
      float e   = __expf(-s);
      float sil = s * __builtin_amdgcn_rcpf(1.0f + e);
      float tt  = fmaf(s, (1.0f / 2.4f), 2.5f);   // (s+6)/2.4 in [0,5]
      float cf  = fminf(floorf(tt), 4.0f);
      float u   = tt - cf;
      float a0 = A0[0], a1 = A1[0], a2 = A2[0], a3 = A3[0];
      a0 = cf >= 0.5f ? A0[1] : a0;  a1 = cf >= 0.5f ? A1[1] : a1;
      a2 = cf >= 0.5f ? A2[1] : a2;  a3 = cf >= 0.5f ? A3[1] : a3;
      a0 = cf >= 1.5f ? A0[2] : a0;  a1 = cf >= 1.5f ? A1[2] : a1;
      a2 = cf >= 1.5f ? A2[2] : a2;  a3 = cf >= 1.5f ? A3[2] : a3;
      a0 = cf >= 2.5f ? A0[3] : a0;  a1 = cf >= 2.5f ? A1[3] : a1;
      a2 = cf >= 2.5f ? A2[3] : a2;  a3 = cf >= 2.5f ? A3[3] : a3;
      a0 = cf >= 3.5f ? A0[4] : a0;  a1 = cf >= 3.5f ? A1[4] : a1;
      a2 = cf >= 3.5f ? A2[4] : a2;  a3 = cf >= 3.5f ? A3[4] : a3;
      float spl = fmaf(fmaf(fmaf(a3, u, a2), u, a1), u, a0);  // includes -Bnd
      float kan = fmaf(bw, sil, spl);
      unsigned short pu = f2h(__expf(kan));
      ph[r] = pu;
      ssum += h2f(pu);          // SAME rounded value PV consumes
    }
    union { half4 v; unsigned int u[2]; } Pb;
    Pb.u[0] = (unsigned int)ph[0] | ((unsigned int)ph[1] << 16);
    Pb.u[1] = (unsigned int)ph[2] | ((unsigned int)ph[3] << 16);
    // Pb is the B-operand fragment: col q = lr, k-elem j = key k0+4*lg+j

    // ---- PV: O^T += V^T · P^T  (A = V^T rows d=lr / 16+lr) ----
    const half4 Av_h0 = ldh4(vh0 + k0 + ko);
    const half4 Av_l0 = ldh4(vl0 + k0 + ko);
    const half4 Av_h1 = ldh4(vh1 + k0 + ko);
    const half4 Av_l1 = ldh4(vl1 + k0 + ko);
    accO0 = MFMA16(Av_h0, Pb.v, accO0);
    accO0 = MFMA16(Av_l0, Pb.v, accO0);
    accO1 = MFMA16(Av_h1, Pb.v, accO1);
    accO1 = MFMA16(Av_l1, Pb.v, accO1);
  }

  // ---- 8-way combine ----
  #pragma unroll
  for (int r = 0; r < 4; ++r) {
    DlO[w][4 * lg + r][lr]      = accO0[r];   // accO[r]: d = 4*lg+r, q = lr
    DlO[w][16 + 4 * lg + r][lr] = accO1[r];
  }
  DlS[w][lg][lr] = ssum;
  __syncthreads();

  {
    const int q = tid & 15;
    const int d = tid >> 4;     // 0..31 (512 threads)
    float o = 0.f, sden = 0.f;
    #pragma unroll
    for (int ww = 0; ww < 8; ++ww) {
      o += DlO[ww][d][q];
      #pragma unroll
      for (int g = 0; g < 4; ++g) sden += DlS[ww][g][q];
    }
    Onorm[((size_t)bh * DH + d) * NPOS + q0 + q] = o / sden;
  }
}

// ---------------------------------------------------------------------------
// Kernel C: output projection with Onorm tile staged in LDS.
// out[b,c,n] = sum_i Wo[c,i] * Onorm[b*128+i][n]; Wo via s_loads.
// ---------------------------------------------------------------------------
__global__ __launch_bounds__(256) void outproj_kernel(
    const float* __restrict__ Onorm, const float* __restrict__ Wo,
    float* __restrict__ out)
{
  __shared__ float os[INNER][64];   // 32 KB

  const int tid  = threadIdx.x;
  const int lane = tid & 63;
  const int it   = __builtin_amdgcn_readfirstlane(tid >> 6); // SGPR
  const int n    = blockIdx.x * 64 + lane;
  const int c0   = blockIdx.y * 16 + it * 4;   // wave-uniform SGPR
  const int b    = blockIdx.z;

  const float* ob = Onorm + (size_t)b * INNER * NPOS + (size_t)blockIdx.x * 64;
  const float* w0 = Wo + (size_t)c0 * INNER;

  // stage 128i x 64n: 8 float4 per thread, coalesced
  {
    const int srow = tid >> 4;
    const int scol = (tid & 15) * 4;
    #pragma unroll
    for (int j = 0; j < 8; ++j) {
      const int r = srow + 16 * j;
      *(float4*)&os[r][scol] =
          *(const float4*)&ob[(size_t)r * NPOS + scol];
    }
  }
  __syncthreads();

  float acc[4] = {0.f, 0.f, 0.f, 0.f};

  #pragma unroll 16
  for (int i = 0; i < INNER; ++i) {
    const float xv = os[i][lane];
    acc[0] += w0[i]             * xv;
    acc[1] += w0[INNER + i]     * xv;
    acc[2] += w0[2 * INNER + i] * xv;
    acc[3] += w0[3 * INNER + i] * xv;
  }
  #pragma unroll
  for (int j = 0; j < 4; ++j)
    out[((size_t)(b * CH + c0 + j)) * NPOS + n] = acc[j];
}

// ---------------------------------------------------------------------------
extern "C" void kernel_launch(void* const* d_in, const int* in_sizes, int n_in,
                              void* d_out, int out_size, void* d_ws, size_t ws_size,
                              hipStream_t stream)
{
  const float* x  = (const float*)d_in[0];
  const float* Wq = (const float*)d_in[1];
  const float* Wk = (const float*)d_in[2];
  const float* Wv = (const float*)d_in[3];
  const float* Wo = (const float*)d_in[4];
  const float* bw = (const float*)d_in[5];
  const float* sw = (const float*)d_in[6];
  const float* ss = (const float*)d_in[7];
  float* out = (float*)d_out;

  // workspace: Onorm (f32, 1MB) | 6x f16 QKV (512KB each)
  float* Onorm = (float*)d_ws;
  unsigned short* base = (unsigned short*)(Onorm + (size_t)NBH * DH * NPOS);
  const size_t QKN = (size_t)NBH * NPOS * DH;   // 262144 elements
  unsigned short* Qhi  = base;
  unsigned short* Qlo  = Qhi  + QKN;
  unsigned short* Khi  = Qlo  + QKN;
  unsigned short* Klo  = Khi  + QKN;
  unsigned short* Vthi = Klo  + QKN;
  unsigned short* Vtlo = Vthi + QKN;

  proj_kernel<<<dim3(16, 16, 2), 256, 0, stream>>>(
      x, Wq, Wk, Wv, Qhi, Qlo, Khi, Klo, Vthi, Vtlo);
  attn_fused<<<dim3(8, 64), 512, 0, stream>>>(
      Qhi, Qlo, Khi, Klo, Vthi, Vtlo, bw, sw, ss, Onorm);
  outproj_kernel<<<dim3(16, 16, 2), 256, 0, stream>>>(Onorm, Wo, out);
}

// Round 12
// 48.938 us; speedup vs baseline: 1.3042x; 1.3042x over previous
//
#include <hip/hip_runtime.h>
#include <math.h>

#define NPOS 1024   // H*W
#define DH   32     // dim head
#define NBH  8      // B * HEADS
#define CH   256
#define INNER 128   // HEADS*DIM_HEAD

typedef __attribute__((ext_vector_type(4))) _Float16 half4;
typedef __attribute__((ext_vector_type(4))) float f32x4;

// Canonical CDNA 16x16x16 f16 MFMA.  A: row=l&15, k=4*(l>>4)+j.  B: col=l&15,
// same k ordering.  C/D: col=l&15, row=(l>>4)*4+reg.
#define MFMA16(a, b, c) __builtin_amdgcn_mfma_f32_16x16x16f16((a), (b), (c), 0, 0, 0)

union h2u { _Float16 h; unsigned short u; };

__device__ __forceinline__ unsigned short f2h(float f) {
  h2u c; c.h = (_Float16)f; return c.u;
}
__device__ __forceinline__ float h2f(unsigned short u) {
  h2u c; c.u = u; return (float)c.h;
}
__device__ __forceinline__ half4 ldh4(const unsigned short* __restrict__ p) {
  union { half4 v; uint2 u; } r;
  r.u = *(const uint2*)p;
  return r.v;
}

// ---------------------------------------------------------------------------
// Kernel A: fused QKV projection + split-f16 encode.
// 8-wave WG: 4 i-groups x 2 c-halves (in-WG K-split doubles wave-level
// parallelism to hide s_load latency).  Weights via wave-uniform s_loads;
// x per-lane coalesced VMEM.  kh=1 waves dump partials to LDS; kh=0 combine
// + encode.  Qhi/Qlo/Khi/Klo: [bh][n][d]; Vthi/Vtlo: [bh][d][n].
// ---------------------------------------------------------------------------
__global__ __launch_bounds__(512) void proj_kernel(
    const float* __restrict__ x, const float* __restrict__ Wq,
    const float* __restrict__ Wk, const float* __restrict__ Wv,
    unsigned short* __restrict__ Qhi, unsigned short* __restrict__ Qlo,
    unsigned short* __restrict__ Khi, unsigned short* __restrict__ Klo,
    unsigned short* __restrict__ Vthi, unsigned short* __restrict__ Vtlo)
{
  __shared__ float part[4][6][64];   // [i-group][acc][lane], 6 KB

  const int tid  = threadIdx.x;
  const int lane = tid & 63;
  const int wid  = __builtin_amdgcn_readfirstlane(tid >> 6); // 0..7 SGPR
  const int it   = wid & 3;        // i-group
  const int kh   = wid >> 2;       // c-half
  const int n    = blockIdx.x * 64 + lane;  // 0..1023
  const int i0   = blockIdx.y * 8 + it * 2; // even, 0..126 (wave-uniform)
  const int b    = blockIdx.z;

  const float* xb = x  + (size_t)b * CH * NPOS + n;
  const float* wq = Wq + (size_t)i0 * CH;
  const float* wk = Wk + (size_t)i0 * CH;
  const float* wv = Wv + (size_t)i0 * CH;

  float aq0 = 0.f, aq1 = 0.f, ak0 = 0.f, ak1 = 0.f, av0 = 0.f, av1 = 0.f;

  const int cbase = kh * 128;
  #pragma unroll 16
  for (int cc = 0; cc < 128; ++cc) {
    const int c = cbase + cc;
    const float xv = xb[(size_t)c * NPOS];
    aq0 += wq[c]      * xv;
    aq1 += wq[CH + c] * xv;
    ak0 += wk[c]      * xv;
    ak1 += wk[CH + c] * xv;
    av0 += wv[c]      * xv;
    av1 += wv[CH + c] * xv;
  }

  if (kh == 1) {
    part[it][0][lane] = aq0;  part[it][1][lane] = aq1;
    part[it][2][lane] = ak0;  part[it][3][lane] = ak1;
    part[it][4][lane] = av0;  part[it][5][lane] = av1;
  }
  __syncthreads();
  if (kh == 1) return;

  aq0 += part[it][0][lane];  aq1 += part[it][1][lane];
  ak0 += part[it][2][lane];  ak1 += part[it][3][lane];
  av0 += part[it][4][lane];  av1 += part[it][5][lane];

  const float qs = 0.17677669529663687f;  // 1/sqrt(32)
  aq0 *= qs;  aq1 *= qs;

  const int h = i0 >> 5, d = i0 & 31, bh = b * 4 + h;

  unsigned short qh0 = f2h(aq0), qh1 = f2h(aq1);
  unsigned short ql0 = f2h(aq0 - h2f(qh0)), ql1 = f2h(aq1 - h2f(qh1));
  unsigned short kh0v = f2h(ak0), kh1v = f2h(ak1);
  unsigned short kl0 = f2h(ak0 - h2f(kh0v)), kl1 = f2h(ak1 - h2f(kh1v));
  unsigned short vh0 = f2h(av0), vh1 = f2h(av1);
  unsigned short vl0 = f2h(av0 - h2f(vh0)), vl1 = f2h(av1 - h2f(vh1));

  const size_t qk = ((size_t)bh * NPOS + n) * DH + d;   // d even -> 4B aligned
  *(unsigned int*)(Qhi + qk) = (unsigned int)qh0 | ((unsigned int)qh1 << 16);
  *(unsigned int*)(Qlo + qk) = (unsigned int)ql0 | ((unsigned int)ql1 << 16);
  *(unsigned int*)(Khi + qk) = (unsigned int)kh0v | ((unsigned int)kh1v << 16);
  *(unsigned int*)(Klo + qk) = (unsigned int)kl0 | ((unsigned int)kl1 << 16);

  const size_t vt = ((size_t)bh * DH + d) * NPOS + n;
  Vthi[vt]        = vh0;
  Vthi[vt + NPOS] = vh1;
  Vtlo[vt]        = vl0;
  Vtlo[vt + NPOS] = vl1;
}

// ---------------------------------------------------------------------------
// Kernel B: fully fused attention (UNCHANGED from passing R9/R10/R11 version).
// S^T = K·Q^T; KAN + exp(kan-Bnd) in-register; f16 P = B-operand fragment
// for O^T = V^T·P^T; denominator sums same f16-rounded p; 8-way LDS combine.
// ---------------------------------------------------------------------------
__global__ __launch_bounds__(512) void attn_fused(
    const unsigned short* __restrict__ Qhi, const unsigned short* __restrict__ Qlo,
    const unsigned short* __restrict__ Khi, const unsigned short* __restrict__ Klo,
    const unsigned short* __restrict__ Vthi, const unsigned short* __restrict__ Vtlo,
    const float* __restrict__ bwp, const float* __restrict__ swp,
    const float* __restrict__ ssp, float* __restrict__ Onorm)
{
  __shared__ float DlO[8][32][17];
  __shared__ float DlS[8][4][17];

  const int tid = threadIdx.x;
  const int l   = tid & 63;
  const int w   = tid >> 6;        // 0..7
  const int lr  = l & 15;
  const int lg  = l >> 4;          // 0..3
  const int ko  = lg * 4;
  const int bh  = blockIdx.x;      // 0..7 (== XCD)
  const int q0  = blockIdx.y * 16;

  // ---- uniform KAN constants ----
  const float sc = ssp[0];
  const float bw = bwp[0];
  float C[8];
  #pragma unroll
  for (int j = 0; j < 8; ++j) C[j] = swp[j] * sc;
  float maxc = 0.f;
  #pragma unroll
  for (int j = 0; j < 8; ++j) maxc = fmaxf(maxc, fabsf(C[j]));
  const float Bnd = fabsf(bw) * 6.0f + maxc;    // >= max_x kan(x)

  float A0[5], A1[5], A2[5], A3[5];             // per-cell cubic; -Bnd in A0
  #pragma unroll
  for (int c = 0; c < 5; ++c) {
    A0[c] = (C[c] + 4.f * C[c+1] + C[c+2]) * (1.f / 6.f) - Bnd;
    A1[c] = (-3.f * C[c] + 3.f * C[c+2]) * (1.f / 6.f);
    A2[c] = (3.f * C[c] - 6.f * C[c+1] + 3.f * C[c+2]) * (1.f / 6.f);
    A3[c] = (-C[c] + 3.f * C[c+1] - 3.f * C[c+2] + C[c+3]) * (1.f / 6.f);
  }

  // ---- Q fragments (B-operand, persistent): col q = q0+lr, k-dim d ----
  const size_t qb = ((size_t)bh * NPOS + q0 + lr) * DH;
  const half4 Bq_h0 = ldh4(Qhi + qb + ko);
  const half4 Bq_h1 = ldh4(Qhi + qb + 16 + ko);
  const half4 Bq_l0 = ldh4(Qlo + qb + ko);
  const half4 Bq_l1 = ldh4(Qlo + qb + 16 + ko);

  // ---- V^T bases (A-operand): row d = lr (+16), k = key ----
  const unsigned short* vh0 = Vthi + ((size_t)bh * DH + lr) * NPOS;
  const unsigned short* vh1 = vh0 + (size_t)16 * NPOS;
  const unsigned short* vl0 = Vtlo + ((size_t)bh * DH + lr) * NPOS;
  const unsigned short* vl1 = vl0 + (size_t)16 * NPOS;

  f32x4 accO0 = {0.f, 0.f, 0.f, 0.f};   // d 0..15
  f32x4 accO1 = {0.f, 0.f, 0.f, 0.f};   // d 16..31
  float ssum = 0.f;

  #pragma unroll 2
  for (int t = 0; t < 8; ++t) {
    const int k0 = w * 128 + t * 16;

    // ---- QK: A = K rows k0+lr ----
    const size_t kb2 = ((size_t)bh * NPOS + k0 + lr) * DH;
    const half4 Ak_h0 = ldh4(Khi + kb2 + ko);
    const half4 Ak_h1 = ldh4(Khi + kb2 + 16 + ko);
    const half4 Ak_l0 = ldh4(Klo + kb2 + ko);
    const half4 Ak_l1 = ldh4(Klo + kb2 + 16 + ko);

    f32x4 acc = {0.f, 0.f, 0.f, 0.f};
    acc = MFMA16(Ak_h0, Bq_h0, acc);
    acc = MFMA16(Ak_h1, Bq_h1, acc);
    acc = MFMA16(Ak_h0, Bq_l0, acc);
    acc = MFMA16(Ak_h1, Bq_l1, acc);
    acc = MFMA16(Ak_l0, Bq_h0, acc);
    acc = MFMA16(Ak_l1, Bq_h1, acc);
    // acc[r] = S[q=q0+lr][k = k0+4*lg+r]

    // ---- KAN + exp(kan - Bnd) on 4 values; keep f16-consistent p ----
    unsigned short ph[4];
    #pragma unroll
    for (int r = 0; r < 4; ++r) {
      float s = acc[r];
      s = fminf(fmaxf(s, -6.0f), 6.0f);
      float e   = __expf(-s);
      float sil = s * __builtin_amdgcn_rcpf(1.0f + e);
      float tt  = fmaf(s, (1.0f / 2.4f), 2.5f);   // (s+6)/2.4 in [0,5]
      float cf  = fminf(floorf(tt), 4.0f);
      float u   = tt - cf;
      float a0 = A0[0], a1 = A1[0], a2 = A2[0], a3 = A3[0];
      a0 = cf >= 0.5f ? A0[1] : a0;  a1 = cf >= 0.5f ? A1[1] : a1;
      a2 = cf >= 0.5f ? A2[1] : a2;  a3 = cf >= 0.5f ? A3[1] : a3;
      a0 = cf >= 1.5f ? A0[2] : a0;  a1 = cf >= 1.5f ? A1[2] : a1;
      a2 = cf >= 1.5f ? A2[2] : a2;  a3 = cf >= 1.5f ? A3[2] : a3;
      a0 = cf >= 2.5f ? A0[3] : a0;  a1 = cf >= 2.5f ? A1[3] : a1;
      a2 = cf >= 2.5f ? A2[3] : a2;  a3 = cf >= 2.5f ? A3[3] : a3;
      a0 = cf >= 3.5f ? A0[4] : a0;  a1 = cf >= 3.5f ? A1[4] : a1;
      a2 = cf >= 3.5f ? A2[4] : a2;  a3 = cf >= 3.5f ? A3[4] : a3;
      float spl = fmaf(fmaf(fmaf(a3, u, a2), u, a1), u, a0);  // includes -Bnd
      float kan = fmaf(bw, sil, spl);
      unsigned short pu = f2h(__expf(kan));
      ph[r] = pu;
      ssum += h2f(pu);          // SAME rounded value PV consumes
    }
    union { half4 v; unsigned int u[2]; } Pb;
    Pb.u[0] = (unsigned int)ph[0] | ((unsigned int)ph[1] << 16);
    Pb.u[1] = (unsigned int)ph[2] | ((unsigned int)ph[3] << 16);
    // Pb is the B-operand fragment: col q = lr, k-elem j = key k0+4*lg+j

    // ---- PV: O^T += V^T · P^T  (A = V^T rows d=lr / 16+lr) ----
    const half4 Av_h0 = ldh4(vh0 + k0 + ko);
    const half4 Av_l0 = ldh4(vl0 + k0 + ko);
    const half4 Av_h1 = ldh4(vh1 + k0 + ko);
    const half4 Av_l1 = ldh4(vl1 + k0 + ko);
    accO0 = MFMA16(Av_h0, Pb.v, accO0);
    accO0 = MFMA16(Av_l0, Pb.v, accO0);
    accO1 = MFMA16(Av_h1, Pb.v, accO1);
    accO1 = MFMA16(Av_l1, Pb.v, accO1);
  }

  // ---- 8-way combine ----
  #pragma unroll
  for (int r = 0; r < 4; ++r) {
    DlO[w][4 * lg + r][lr]      = accO0[r];   // accO[r]: d = 4*lg+r, q = lr
    DlO[w][16 + 4 * lg + r][lr] = accO1[r];
  }
  DlS[w][lg][lr] = ssum;
  __syncthreads();

  {
    const int q = tid & 15;
    const int d = tid >> 4;     // 0..31 (512 threads)
    float o = 0.f, sden = 0.f;
    #pragma unroll
    for (int ww = 0; ww < 8; ++ww) {
      o += DlO[ww][d][q];
      #pragma unroll
      for (int g = 0; g < 4; ++g) sden += DlS[ww][g][q];
    }
    Onorm[((size_t)bh * DH + d) * NPOS + q0 + q] = o / sden;
  }
}

// ---------------------------------------------------------------------------
// Kernel C: output projection, 8-wave WG: 4 c-groups x 2 i-halves (K-split).
// out[b,c,n] = sum_i Wo[c,i] * Onorm[b*128+i][n]; Wo via s_loads.
// ---------------------------------------------------------------------------
__global__ __launch_bounds__(512) void outproj_kernel(
    const float* __restrict__ Onorm, const float* __restrict__ Wo,
    float* __restrict__ out)
{
  __shared__ float part[4][4][64];   // [c-group][acc][lane], 4 KB

  const int tid  = threadIdx.x;
  const int lane = tid & 63;
  const int wid  = __builtin_amdgcn_readfirstlane(tid >> 6); // 0..7 SGPR
  const int it   = wid & 3;
  const int kh   = wid >> 2;
  const int n    = blockIdx.x * 64 + lane;
  const int c0   = blockIdx.y * 16 + it * 4;   // wave-uniform SGPR
  const int b    = blockIdx.z;

  const float* ob = Onorm + (size_t)b * INNER * NPOS + n;
  const float* w0 = Wo + (size_t)c0 * INNER;

  float acc[4] = {0.f, 0.f, 0.f, 0.f};

  const int ibase = kh * 64;
  #pragma unroll 16
  for (int ii = 0; ii < 64; ++ii) {
    const int i = ibase + ii;
    const float xv = ob[(size_t)i * NPOS];
    acc[0] += w0[i]             * xv;
    acc[1] += w0[INNER + i]     * xv;
    acc[2] += w0[2 * INNER + i] * xv;
    acc[3] += w0[3 * INNER + i] * xv;
  }

  if (kh == 1) {
    #pragma unroll
    for (int j = 0; j < 4; ++j) part[it][j][lane] = acc[j];
  }
  __syncthreads();
  if (kh == 1) return;

  #pragma unroll
  for (int j = 0; j < 4; ++j) acc[j] += part[it][j][lane];

  #pragma unroll
  for (int j = 0; j < 4; ++j)
    out[((size_t)(b * CH + c0 + j)) * NPOS + n] = acc[j];
}

// ---------------------------------------------------------------------------
extern "C" void kernel_launch(void* const* d_in, const int* in_sizes, int n_in,
                              void* d_out, int out_size, void* d_ws, size_t ws_size,
                              hipStream_t stream)
{
  const float* x  = (const float*)d_in[0];
  const float* Wq = (const float*)d_in[1];
  const float* Wk = (const float*)d_in[2];
  const float* Wv = (const float*)d_in[3];
  const float* Wo = (const float*)d_in[4];
  const float* bw = (const float*)d_in[5];
  const float* sw = (const float*)d_in[6];
  const float* ss = (const float*)d_in[7];
  float* out = (float*)d_out;

  // workspace: Onorm (f32, 1MB) | 6x f16 QKV (512KB each)
  float* Onorm = (float*)d_ws;
  unsigned short* base = (unsigned short*)(Onorm + (size_t)NBH * DH * NPOS);
  const size_t QKN = (size_t)NBH * NPOS * DH;   // 262144 elements
  unsigned short* Qhi  = base;
  unsigned short* Qlo  = Qhi  + QKN;
  unsigned short* Khi  = Qlo  + QKN;
  unsigned short* Klo  = Khi  + QKN;
  unsigned short* Vthi = Klo  + QKN;
  unsigned short* Vtlo = Vthi + QKN;

  proj_kernel<<<dim3(16, 16, 2), 512, 0, stream>>>(
      x, Wq, Wk, Wv, Qhi, Qlo, Khi, Klo, Vthi, Vtlo);
  attn_fused<<<dim3(8, 64), 512, 0, stream>>>(
      Qhi, Qlo, Khi, Klo, Vthi, Vtlo, bw, sw, ss, Onorm);
  outproj_kernel<<<dim3(16, 16, 2), 512, 0, stream>>>(Onorm, Wo, out);
}